// Round 5
// baseline (352.586 us; speedup 1.0000x reference)
//
#include <hip/hip_runtime.h>

typedef short v8s __attribute__((ext_vector_type(8)));
typedef float v2f __attribute__((ext_vector_type(2)));
typedef float v4f __attribute__((ext_vector_type(4)));
typedef float f32x16 __attribute__((ext_vector_type(16)));
typedef unsigned int v4u __attribute__((ext_vector_type(4)));
typedef unsigned short ushort_t;

#define NC 256
#define ND 128

__device__ __forceinline__ unsigned short f2bf(float f) {
  union { float f; unsigned int u; } v; v.f = f;
  unsigned int u = v.u;
  unsigned int r = (u + 0x7fffu + ((u >> 16) & 1u)) >> 16;
  return (unsigned short)r;
}

__device__ __forceinline__ unsigned int cvt_pk_bf16(float a, float b) {
  unsigned int r;
  asm("v_cvt_pk_bf16_f32 %0, %1, %2" : "=v"(r) : "v"(a), "v"(b));
  return r;
}

__device__ __forceinline__ float bf_lo(unsigned int u) { return __uint_as_float(u << 16); }
__device__ __forceinline__ float bf_hi(unsigned int u) { return __uint_as_float(u & 0xffff0000u); }

// ---------------- prep: fragment-arranged bf16 P/G/PT, norms, gate (unchanged) --------
__global__ void som_prep_kernel(const float* __restrict__ P, const float* __restrict__ G,
                                const float* __restrict__ gate_logits,
                                ushort_t* __restrict__ PbfA, ushort_t* __restrict__ GbfA,
                                ushort_t* __restrict__ PTbfA,
                                float* __restrict__ b2p, float* __restrict__ b2g,
                                float* __restrict__ gatev) {
  int c = blockIdx.x;      // 0..255
  int t = threadIdx.x;     // 0..127 (= d / k index)
  float p = P[c * ND + t];
  float g = G[c * ND + t];

  int ct = c >> 5, l31 = c & 31;
  int s = t >> 4, hia = (t >> 3) & 1, j = t & 7;
  int lane = l31 + 32 * hia;
  PbfA[((ct * 8 + s) * 64 + lane) * 8 + j] = f2bf(p);
  GbfA[((ct * 8 + s) * 64 + lane) * 8 + j] = f2bf(g);

  int dt = t >> 5, l31d = t & 31;
  int sc = c >> 4, hic = (c >> 3) & 1, jc = c & 7;
  int laned = l31d + 32 * hic;
  PTbfA[((dt * 16 + sc) * 64 + laned) * 8 + jc] = f2bf(p);

  float pp = p * p, gg = g * g;
  #pragma unroll
  for (int m = 1; m < 64; m <<= 1) { pp += __shfl_xor(pp, m); gg += __shfl_xor(gg, m); }
  __shared__ float sp[2], sg[2];
  if ((t & 63) == 0) { sp[t >> 6] = pp; sg[t >> 6] = gg; }
  __syncthreads();
  if (t == 0) {
    b2p[c] = sp[0] + sp[1];
    b2g[c] = sg[0] + sg[1];
    gatev[c] = 1.f / (1.f + expf(-gate_logits[c]));
  }
}

// ---------------- kernel 1: S = X * P^T orientation; u -> blend-A stash ----------------
// 1 wave = 32 rows. C/D: col = c = lane&31, row m = (r&3)+8*(r>>2)+4*hi (on regs).
// u (= e*gate) transposed per-ct via [32c][33m] LDS tile into blend-A-frag stash
// (layout [s2][lane][16B], coalesced). Stash aliases blended rows of the same group.
__global__ __launch_bounds__(256, 4) void som_dist_kernel(
    const float* __restrict__ x,
    const ushort_t* __restrict__ PbfA,
    const ushort_t* __restrict__ GbfA,
    const float* __restrict__ b2p,
    const float* __restrict__ b2g,
    const float* __restrict__ gatev,
    const float* __restrict__ temp_raw,
    float* __restrict__ stash_base,          // = blended region
    float* __restrict__ scalev)
{
  __shared__ float lds[2][4][32 * 33];
  const int tid  = threadIdx.x;
  const int wid  = tid >> 6;
  const int lane = tid & 63;
  const int l31  = lane & 31;
  const int hi   = lane >> 5;
  const int g    = blockIdx.x * 4 + wid;
  const long long R = (long long)g * 32;

  float traw = temp_raw[0];
  float sgm = 1.f / (1.f + __builtin_amdgcn_exp2f(-traw * 1.44269504f));
  float T = sgm * (1.f - 1e-3f) + 1e-3f;
  float k2 = 1.44269504f / T;                 // e = exp2(-d * k2)

  // ---- X A-fragments (row m = l31, k-chunk hi*8+j at step s) + exact f32 row norm ----
  const float* xr = x + (R + l31) * ND + hi * 8;
  v8s xb[8];
  float a2 = 0.f;
  #pragma unroll
  for (int s = 0; s < 8; ++s) {
    v4f lo = *(const v4f*)(xr + s * 16);
    v4f h4 = *(const v4f*)(xr + s * 16 + 4);
    v4u w;
    w[0] = cvt_pk_bf16(lo[0], lo[1]);
    w[1] = cvt_pk_bf16(lo[2], lo[3]);
    w[2] = cvt_pk_bf16(h4[0], h4[1]);
    w[3] = cvt_pk_bf16(h4[2], h4[3]);
    xb[s] = __builtin_bit_cast(v8s, w);
    #pragma unroll
    for (int j = 0; j < 4; ++j) {
      a2 = fmaf(lo[j], lo[j], a2);
      a2 = fmaf(h4[j], h4[j], a2);
    }
  }
  a2 += __shfl_xor(a2, 32);                   // full row norm of row l31, in all lanes

  float tp[16];                                // Σ_c e*(gate+1e-8) per reg-row
  #pragma unroll
  for (int r = 0; r < 16; ++r) tp[r] = 0.f;

  const ushort_t* pb = PbfA + lane * 8;
  const ushort_t* gb = GbfA + lane * 8;

  #pragma unroll
  for (int ct = 0; ct < 8; ++ct) {
    f32x16 aP, aG;
    #pragma unroll
    for (int i = 0; i < 16; ++i) { aP[i] = 0.f; aG[i] = 0.f; }
    #pragma unroll
    for (int s = 0; s < 8; ++s) {
      v8s bp_ = *(const v8s*)(pb + (ct * 8 + s) * 512);   // B: col=c=lane31, k=d
      v8s bg_ = *(const v8s*)(gb + (ct * 8 + s) * 512);
      aP = __builtin_amdgcn_mfma_f32_32x32x16_bf16(xb[s], bp_, aP, 0, 0, 0);
      aG = __builtin_amdgcn_mfma_f32_32x32x16_bf16(xb[s], bg_, aG, 0, 0, 0);
    }
    float bpc = b2p[ct * 32 + l31];
    float bgc = b2g[ct * 32 + l31];
    float gtc = gatev[ct * 32 + l31];
    float* wl = lds[ct & 1][wid];
    #pragma unroll
    for (int r = 0; r < 16; ++r) {
      int mr = (r & 3) + 8 * (r >> 2) + 4 * hi;           // row of this reg
      float a2m = __shfl(a2, mr | (lane & 32));           // ||x_row||^2 for reg-row
      float d2a = fmaf(-2.f, aP[r], a2m + bpc);
      float d2b = fmaf(-2.f, aG[r], a2m + bgc);
      float d = __builtin_amdgcn_sqrtf(fmaxf(d2a, 1e-12f))
              + __builtin_amdgcn_sqrtf(fmaxf(d2b, 1e-12f));
      float e = __builtin_amdgcn_exp2f(-d * k2);
      tp[r] = fmaf(e, gtc + 1e-8f, tp[r]);
      wl[l31 * 33 + mr] = e * gtc;                        // [c][m], conflict-free
    }
    // transpose-read as blend-A fragments (row m = l31, k=c), pack bf16, stash
    #pragma unroll
    for (int h = 0; h < 2; ++h) {
      float f0 = wl[(h * 16 + hi * 8 + 0) * 33 + l31];
      float f1 = wl[(h * 16 + hi * 8 + 1) * 33 + l31];
      float f2 = wl[(h * 16 + hi * 8 + 2) * 33 + l31];
      float f3 = wl[(h * 16 + hi * 8 + 3) * 33 + l31];
      float f4 = wl[(h * 16 + hi * 8 + 4) * 33 + l31];
      float f5 = wl[(h * 16 + hi * 8 + 5) * 33 + l31];
      float f6 = wl[(h * 16 + hi * 8 + 6) * 33 + l31];
      float f7 = wl[(h * 16 + hi * 8 + 7) * 33 + l31];
      v4u pk;
      pk[0] = cvt_pk_bf16(f0, f1);
      pk[1] = cvt_pk_bf16(f2, f3);
      pk[2] = cvt_pk_bf16(f4, f5);
      pk[3] = cvt_pk_bf16(f6, f7);
      *(v4u*)((char*)stash_base + (size_t)g * 16384 + (ct * 2 + h) * 1024 + lane * 16) = pk;
    }
  }
  // reduce tp over the 32 c-lanes (stay within hi-half), store per-row scale
  #pragma unroll
  for (int r = 0; r < 16; ++r) {
    #pragma unroll
    for (int m = 1; m < 32; m <<= 1) tp[r] += __shfl_xor(tp[r], m);
    if (l31 == 0) {
      int mr = (r & 3) + 8 * (r >> 2) + 4 * hi;
      scalev[R + mr] = 1.f / (tp[r] + 1e-16f);            // w = u * scale (exact algebra)
    }
  }
}

// ---------------- kernel 2: blend GEMM + w emit (all coalesced) ----------------
__global__ __launch_bounds__(256, 4) void som_blend_kernel(
    const ushort_t* __restrict__ PTbfA,
    const float* __restrict__ scalev,
    float* __restrict__ blended_out,
    float* __restrict__ w_out)
{
  __shared__ float lds2[2][4][32 * 18];
  const int tid  = threadIdx.x;
  const int wid  = tid >> 6;
  const int lane = tid & 63;
  const int l31  = lane & 31;
  const int hi   = lane >> 5;
  const int g    = blockIdx.x * 4 + wid;
  const long long R = (long long)g * 32;

  float sc = scalev[R + l31];                  // scale for row l31 (A-frag row)
  float scr[16];
  #pragma unroll
  for (int r = 0; r < 16; ++r) {
    int mr = (r & 3) + 8 * (r >> 2) + 4 * hi;
    scr[r] = __shfl(sc, mr | (lane & 32));     // scale for reg-row mr
  }

  f32x16 acc[4];
  #pragma unroll
  for (int dt = 0; dt < 4; ++dt)
    #pragma unroll
    for (int i = 0; i < 16; ++i) acc[dt][i] = 0.f;

  const ushort_t* tb = PTbfA + lane * 8;
  #pragma unroll
  for (int s2 = 0; s2 < 16; ++s2) {
    // blend A-frag (row m=l31, k=c chunk), coalesced 1KB wave load from stash
    v4u af = *(const v4u*)((const char*)blended_out + (size_t)g * 16384 + s2 * 1024 + lane * 16);
    v8s afr = __builtin_bit_cast(v8s, af);
    #pragma unroll
    for (int dt = 0; dt < 4; ++dt) {
      v8s pf = *(const v8s*)(tb + (dt * 16 + s2) * 512);  // B: col=d, k=c
      acc[dt] = __builtin_amdgcn_mfma_f32_32x32x16_bf16(afr, pf, acc[dt], 0, 0, 0);
    }
    // w emit: lane holds w[l31][s2*16 + hi*8 + 0..7]; transpose via [32m][18c] LDS
    float* wl = lds2[s2 & 1][wid];
    #pragma unroll
    for (int w = 0; w < 4; ++w) {
      v2f p2;
      p2[0] = bf_lo(af[w]) * sc;
      p2[1] = bf_hi(af[w]) * sc;
      *(v2f*)(wl + l31 * 18 + hi * 8 + 2 * w) = p2;
    }
    #pragma unroll
    for (int t2 = 0; t2 < 4; ++t2) {
      int row = (lane >> 3) + t2 * 8;
      v2f q = *(const v2f*)(wl + row * 18 + (lane & 7) * 2);
      *(v2f*)(w_out + (size_t)(R + row) * NC + s2 * 16 + (lane & 7) * 2) = q;
    }
  }
  // blended stores: row mr on regs, col d = dt*32+l31 -> 2x128B contiguous per instr
  #pragma unroll
  for (int dt = 0; dt < 4; ++dt)
    #pragma unroll
    for (int r = 0; r < 16; ++r) {
      int mr = (r & 3) + 8 * (r >> 2) + 4 * hi;
      blended_out[(size_t)(R + mr) * ND + dt * 32 + l31] = acc[dt][r] * scr[r];
    }
}

extern "C" void kernel_launch(void* const* d_in, const int* in_sizes, int n_in,
                              void* d_out, int out_size, void* d_ws, size_t ws_size,
                              hipStream_t stream) {
  const float* x    = (const float*)d_in[0];
  const float* P    = (const float*)d_in[1];
  const float* G    = (const float*)d_in[2];
  const float* traw = (const float*)d_in[3];
  const float* gl   = (const float*)d_in[4];
  const int N = in_sizes[0] / ND;             // 262144

  char* ws = (char*)d_ws;
  ushort_t* PbfA  = (ushort_t*)(ws);
  ushort_t* GbfA  = (ushort_t*)(ws + 65536);
  ushort_t* PTbfA = (ushort_t*)(ws + 131072);
  float* b2p   = (float*)(ws + 196608);
  float* b2g   = (float*)(ws + 197632);
  float* gatev = (float*)(ws + 198656);
  float* scalev = (float*)(ws + 200704);      // N*4 bytes

  float* blended = (float*)d_out;
  float* wout    = blended + (size_t)N * ND;

  som_prep_kernel<<<NC, ND, 0, stream>>>(P, G, gl, PbfA, GbfA, PTbfA, b2p, b2g, gatev);
  som_dist_kernel<<<N / 128, 256, 0, stream>>>(x, PbfA, GbfA, b2p, b2g, gatev,
                                               traw, blended, scalev);
  som_blend_kernel<<<N / 128, 256, 0, stream>>>(PTbfA, scalev, blended, wout);
}

// Round 6
// 152.329 us; speedup vs baseline: 2.3146x; 2.3146x over previous
//
#include <hip/hip_runtime.h>

typedef short v8s __attribute__((ext_vector_type(8)));
typedef float v4f __attribute__((ext_vector_type(4)));
typedef float f32x16 __attribute__((ext_vector_type(16)));
typedef unsigned int v2u __attribute__((ext_vector_type(2)));
typedef unsigned int v4u __attribute__((ext_vector_type(4)));
typedef unsigned short ushort_t;

#define NC 256
#define ND 128

__device__ __forceinline__ unsigned short f2bf(float f) {
  union { float f; unsigned int u; } v; v.f = f;
  unsigned int u = v.u;
  unsigned int r = (u + 0x7fffu + ((u >> 16) & 1u)) >> 16;
  return (unsigned short)r;
}

__device__ __forceinline__ unsigned int cvt_pk_bf16(float a, float b) {
  unsigned int r;
  asm("v_cvt_pk_bf16_f32 %0, %1, %2" : "=v"(r) : "v"(a), "v"(b));
  return r;
}

__device__ __forceinline__ float bf_lo(unsigned int u) { return __uint_as_float(u << 16); }
__device__ __forceinline__ float bf_hi(unsigned int u) { return __uint_as_float(u & 0xffff0000u); }

// ---------------- prep: fragment-arranged bf16 P/G/PT, norms, gate (unchanged) --------
__global__ void som_prep_kernel(const float* __restrict__ P, const float* __restrict__ G,
                                const float* __restrict__ gate_logits,
                                ushort_t* __restrict__ PbfA, ushort_t* __restrict__ GbfA,
                                ushort_t* __restrict__ PTbfA,
                                float* __restrict__ b2p, float* __restrict__ b2g,
                                float* __restrict__ gatev) {
  int c = blockIdx.x;      // 0..255
  int t = threadIdx.x;     // 0..127 (= d / k index)
  float p = P[c * ND + t];
  float g = G[c * ND + t];

  int ct = c >> 5, l31 = c & 31;
  int s = t >> 4, hia = (t >> 3) & 1, j = t & 7;
  int lane = l31 + 32 * hia;
  PbfA[((ct * 8 + s) * 64 + lane) * 8 + j] = f2bf(p);
  GbfA[((ct * 8 + s) * 64 + lane) * 8 + j] = f2bf(g);

  int dt = t >> 5, l31d = t & 31;
  int sc = c >> 4, hic = (c >> 3) & 1, jc = c & 7;
  int laned = l31d + 32 * hic;
  PTbfA[((dt * 16 + sc) * 64 + laned) * 8 + jc] = f2bf(p);

  float pp = p * p, gg = g * g;
  #pragma unroll
  for (int m = 1; m < 64; m <<= 1) { pp += __shfl_xor(pp, m); gg += __shfl_xor(gg, m); }
  __shared__ float sp[2], sg[2];
  if ((t & 63) == 0) { sp[t >> 6] = pp; sg[t >> 6] = gg; }
  __syncthreads();
  if (t == 0) {
    b2p[c] = sp[0] + sp[1];
    b2g[c] = sg[0] + sg[1];
    gatev[c] = 1.f / (1.f + expf(-gate_logits[c]));
  }
}

// ---------------- fused main kernel ----------------
// 1 wave = 32 rows, S^T orientation (A=P tile 32c x 16k, B=X^T): lane holds col m=l31.
// u (= e*gate, bf16, unscaled) goes to a per-wave 16KB swizzled LDS tile [32 m][256 c].
// Outputs are emitted via LDS transpose as full-128B-line stores (8 rows x 128B / instr).
__global__ __launch_bounds__(256, 2) void som_main_kernel(
    const float* __restrict__ x,
    const ushort_t* __restrict__ PbfA,
    const ushort_t* __restrict__ GbfA,
    const ushort_t* __restrict__ PTbfA,
    const float* __restrict__ b2p,
    const float* __restrict__ b2g,
    const float* __restrict__ gatev,
    const float* __restrict__ temp_raw,
    float* __restrict__ blended_out,
    float* __restrict__ w_out)
{
  __shared__ char smem[65536];                 // 4 waves x 16 KB, per-wave private
  const int tid  = threadIdx.x;
  const int wid  = tid >> 6;
  const int lane = tid & 63;
  const int l31  = lane & 31;
  const int hi   = lane >> 5;
  const long long R = ((long long)blockIdx.x * 4 + wid) * 32;
  char* wl = smem + wid * 16384;
  const int rsw = (l31 & 7) << 4;              // row swizzle for this lane's own row

  float traw = temp_raw[0];
  float sgm = 1.f / (1.f + __builtin_amdgcn_exp2f(-traw * 1.44269504f));
  float T = sgm * (1.f - 1e-3f) + 1e-3f;
  float k2 = 1.44269504f / T;                  // e = exp2(-d * k2)

  // ---- X B-fragments (col m = l31, k = hi*8+j at tile s) + exact f32 row norm ----
  const float* xr = x + (R + l31) * ND + hi * 8;
  v8s xb[8];
  float a2 = 0.f;
  #pragma unroll
  for (int s = 0; s < 8; ++s) {
    v4f lo = *(const v4f*)(xr + s * 16);
    v4f h4 = *(const v4f*)(xr + s * 16 + 4);
    v4u w;
    w[0] = cvt_pk_bf16(lo[0], lo[1]);
    w[1] = cvt_pk_bf16(lo[2], lo[3]);
    w[2] = cvt_pk_bf16(h4[0], h4[1]);
    w[3] = cvt_pk_bf16(h4[2], h4[3]);
    xb[s] = __builtin_bit_cast(v8s, w);
    #pragma unroll
    for (int j = 0; j < 4; ++j) {
      a2 = fmaf(lo[j], lo[j], a2);
      a2 = fmaf(h4[j], h4[j], a2);
    }
  }
  a2 += __shfl_xor(a2, 32);                    // ||x_row||^2, row = l31

  // ---- dist loop: MFMA -> e*gate -> bf16 -> LDS (no register retention) ----
  float s1 = 0.f, su = 0.f;
  const ushort_t* pb = PbfA + lane * 8;
  const ushort_t* gb = GbfA + lane * 8;
  #pragma unroll
  for (int ct = 0; ct < 8; ++ct) {
    f32x16 aP, aG;
    #pragma unroll
    for (int i = 0; i < 16; ++i) { aP[i] = 0.f; aG[i] = 0.f; }
    #pragma unroll
    for (int s = 0; s < 8; ++s) {
      v8s ap = *(const v8s*)(pb + (ct * 8 + s) * 512);
      v8s ag = *(const v8s*)(gb + (ct * 8 + s) * 512);
      aP = __builtin_amdgcn_mfma_f32_32x32x16_bf16(ap, xb[s], aP, 0, 0, 0);
      aG = __builtin_amdgcn_mfma_f32_32x32x16_bf16(ag, xb[s], aG, 0, 0, 0);
    }
    #pragma unroll
    for (int q = 0; q < 4; ++q) {
      int c0 = ct * 32 + q * 8 + hi * 4;
      v4f bp = *(const v4f*)(b2p + c0);
      v4f bg = *(const v4f*)(b2g + c0);
      v4f gt = *(const v4f*)(gatev + c0);
      float uf[4];
      #pragma unroll
      for (int j2 = 0; j2 < 4; ++j2) {
        int r = q * 4 + j2;
        float d2a = fmaf(-2.f, aP[r], a2 + bp[j2]);
        float d2b = fmaf(-2.f, aG[r], a2 + bg[j2]);
        float d = __builtin_amdgcn_sqrtf(fmaxf(d2a, 1e-12f))
                + __builtin_amdgcn_sqrtf(fmaxf(d2b, 1e-12f));
        float e = __builtin_amdgcn_exp2f(-d * k2);
        float uu = e * gt[j2];
        s1 += e; su += uu;
        uf[j2] = uu;
      }
      v2u pk;
      pk[0] = cvt_pk_bf16(uf[0], uf[1]);
      pk[1] = cvt_pk_bf16(uf[2], uf[3]);
      // u[m=l31][c0..c0+3], swizzled b64 write
      *(v2u*)(wl + l31 * 512 + ((ct * 64 + q * 16 + hi * 8) ^ rsw)) = pk;
    }
  }
  s1 += __shfl_xor(s1, 32);
  su += __shfl_xor(su, 32);
  float scale = 1.f / (su + 1e-8f * (s1 + 1e-8f));   // exact algebra of double norm

  // ---- w emit: LDS-transposed, full-128B-line stores (8 rows x 32 c per instr) ----
  #pragma unroll
  for (int p = 0; p < 4; ++p) {
    int row = (lane >> 3) + 8 * p;
    float rsc = __shfl(scale, row);
    float* wdst = w_out + (size_t)(R + row) * NC + (lane & 7) * 4;
    #pragma unroll
    for (int ch = 0; ch < 8; ++ch) {
      v2u pk = *(const v2u*)(wl + row * 512 + ((ch * 64 + (lane & 7) * 8) ^ ((row & 7) << 4)));
      v4f wv;
      wv[0] = bf_lo(pk[0]) * rsc;
      wv[1] = bf_hi(pk[0]) * rsc;
      wv[2] = bf_lo(pk[1]) * rsc;
      wv[3] = bf_hi(pk[1]) * rsc;
      *(v4f*)(wdst + ch * 32) = wv;
    }
  }

  // ---- blend: blended^T = PT(32d x 16c) * U^T(16c x 32m), B-frags from LDS ----
  f32x16 acc[4];
  #pragma unroll
  for (int dt = 0; dt < 4; ++dt)
    #pragma unroll
    for (int i = 0; i < 16; ++i) acc[dt][i] = 0.f;

  const ushort_t* tb = PTbfA + lane * 8;
  #pragma unroll
  for (int s2 = 0; s2 < 16; ++s2) {
    v4u bw = *(const v4u*)(wl + l31 * 512 + ((s2 * 32 + hi * 16) ^ rsw));
    v8s bfrag = __builtin_bit_cast(v8s, bw);
    #pragma unroll
    for (int dt = 0; dt < 4; ++dt) {
      v8s pa = *(const v8s*)(tb + (dt * 16 + s2) * 512);
      acc[dt] = __builtin_amdgcn_mfma_f32_32x32x16_bf16(pa, bfrag, acc[dt], 0, 0, 0);
    }
  }

  // ---- blended emit: scale in-reg, LDS [32 m][128 d] f32 (reuse region), full lines ----
  #pragma unroll
  for (int dt = 0; dt < 4; ++dt) {
    #pragma unroll
    for (int q = 0; q < 4; ++q) {
      v4f ov;
      ov[0] = acc[dt][4 * q + 0] * scale;
      ov[1] = acc[dt][4 * q + 1] * scale;
      ov[2] = acc[dt][4 * q + 2] * scale;
      ov[3] = acc[dt][4 * q + 3] * scale;
      *(v4f*)(wl + l31 * 512 + ((dt * 128 + q * 32 + hi * 16) ^ rsw)) = ov;
    }
  }
  #pragma unroll
  for (int p = 0; p < 4; ++p) {
    int row = (lane >> 3) + 8 * p;
    float* bdst = blended_out + (size_t)(R + row) * ND + (lane & 7) * 4;
    #pragma unroll
    for (int ch = 0; ch < 4; ++ch) {
      v4f bv = *(const v4f*)(wl + row * 512 + ((ch * 128 + (lane & 7) * 16) ^ ((row & 7) << 4)));
      *(v4f*)(bdst + ch * 32) = bv;
    }
  }
}

extern "C" void kernel_launch(void* const* d_in, const int* in_sizes, int n_in,
                              void* d_out, int out_size, void* d_ws, size_t ws_size,
                              hipStream_t stream) {
  const float* x    = (const float*)d_in[0];
  const float* P    = (const float*)d_in[1];
  const float* G    = (const float*)d_in[2];
  const float* traw = (const float*)d_in[3];
  const float* gl   = (const float*)d_in[4];
  const int N = in_sizes[0] / ND;             // 262144

  char* ws = (char*)d_ws;
  ushort_t* PbfA  = (ushort_t*)(ws);
  ushort_t* GbfA  = (ushort_t*)(ws + 65536);
  ushort_t* PTbfA = (ushort_t*)(ws + 131072);
  float* b2p   = (float*)(ws + 196608);
  float* b2g   = (float*)(ws + 197632);
  float* gatev = (float*)(ws + 198656);

  float* blended = (float*)d_out;
  float* wout    = blended + (size_t)N * ND;

  som_prep_kernel<<<NC, ND, 0, stream>>>(P, G, gl, PbfA, GbfA, PTbfA, b2p, b2g, gatev);
  som_main_kernel<<<N / 128, 256, 0, stream>>>(x, PbfA, GbfA, PTbfA, b2p, b2g, gatev,
                                               traw, blended, wout);
}